// Round 2
// baseline (82.292 us; speedup 1.0000x reference)
//
#include <hip/hip_runtime.h>
#include <hip/hip_bf16.h>

typedef __bf16 bf16_t;
typedef bf16_t bf16x2 __attribute__((ext_vector_type(2)));
typedef bf16_t bf16x8 __attribute__((ext_vector_type(8)));
typedef float  floatx4  __attribute__((ext_vector_type(4)));
typedef float  floatx16 __attribute__((ext_vector_type(16)));
typedef int    intx2    __attribute__((ext_vector_type(2)));

constexpr int B = 8, N = 2048, D = 64;

// async global->LDS, 16B per lane. LDS dest = wave-uniform base + lane*16 (HW).
typedef __attribute__((address_space(1))) const void gconst_t;
typedef __attribute__((address_space(3))) void lds_t;
__device__ __forceinline__ void gload_lds16(const void* g, void* l) {
    __builtin_amdgcn_global_load_lds((gconst_t*)g, (lds_t*)l, 16, 0, 0);
}

// --- prepass: emit K and V in MFMA fragment order so the attention loop's
// staging is lane-linear (global_load_lds-compatible, no per-lane scatter).
// KF[b][kvblk][kd][lane][8]  = K[b][kvblk*32 + (lane&31)][kd*16 + (lane>>5)*8 + j]
// VF[b][kvblk][s2*2+dblk][lane][8] = V[b][kvblk*32 + s2*16 + (lane>>5)*8 + j][dblk*32 + (lane&31)]
// grid 512 = [kvblk(64)][b(8)], 256 thr.
__global__ __launch_bounds__(256)
void prepass_kernel(const float* __restrict__ k, const float* __restrict__ v,
                    bf16_t* __restrict__ kf, bf16_t* __restrict__ vf) {
    __shared__ float t[32 * 65];
    const int tid = threadIdx.x;
    const int b   = blockIdx.x & 7;
    const int kvb = blockIdx.x >> 3;                       // 0..63
    const size_t inoff  = ((size_t)b * N + kvb * 32) * D;  // 32x64 fp32 chunk
    const size_t outoff = (size_t)(b * 64 + kvb) * 2048;   // 4x64x8 bf16 frags

    // K: coalesced read, fragment-order 16B write
    {
        const float* src = k + inoff;
        floatx4 f0 = *(const floatx4*)(src + tid * 8);
        floatx4 f1 = *(const floatx4*)(src + tid * 8 + 4);
        bf16x8 o;
        #pragma unroll
        for (int j = 0; j < 4; ++j) { o[j] = (bf16_t)f0[j]; o[j + 4] = (bf16_t)f1[j]; }
        const int rr = tid >> 3, kd = (tid >> 1) & 3, hh = tid & 1;
        *(bf16x8*)(kf + outoff + (size_t)kd * 512 + (hh * 32 + rr) * 8) = o;
    }
    // V: coalesced read -> padded LDS tile -> transposed gather -> coalesced frag write
    {
        const float* src = v + inoff;
        floatx4 f0 = *(const floatx4*)(src + tid * 8);
        floatx4 f1 = *(const floatx4*)(src + tid * 8 + 4);
        const int rr = tid >> 3, cc = (tid & 7) * 8;
        #pragma unroll
        for (int j = 0; j < 4; ++j) { t[rr * 65 + cc + j] = f0[j]; t[rr * 65 + cc + 4 + j] = f1[j]; }
        __syncthreads();
        const int s2 = tid >> 7, dblk = (tid >> 6) & 1, lane = tid & 63;
        const int hh = lane >> 5, l31 = lane & 31;
        bf16x8 o;
        #pragma unroll
        for (int j = 0; j < 8; ++j)
            o[j] = (bf16_t)t[(s2 * 16 + hh * 8 + j) * 65 + dblk * 32 + l31];
        *(bf16x8*)(vf + outoff + (size_t)(s2 * 2 + dblk) * 512 + lane * 8) = o;
    }
}

// --- flash attention, transposed (S^T = K Q^T, O^T = V^T P^T) ---
// grid 512 = [qt(64)][b(8)], 256 thr = 4 kv-slice waves, 16 kvblk-iters each.
// KV staging: per-wave private 2-slot LDS ring (8 KB/slot: kf 4K + vf 4K) filled
// by async global_load_lds (no VGPR dest -> MLP not capped by registers), counted
// s_waitcnt vmcnt(8) so next-slot loads stay in flight across the whole iteration.
// ds_read_b128 at lane*16 is conflict-free. Ring LDS is reused as the merge
// buffer in the epilogue. Q pre-scaled by 0.125*log2(e) -> softmax exp is one
// v_exp_f32; positive scale preserves the ==0 equality-mask semantics.
__global__ __launch_bounds__(256, 2)
void attn_kernel(const float* __restrict__ q, const bf16_t* __restrict__ kf,
                 const bf16_t* __restrict__ vf, float* __restrict__ out) {
    __shared__ __align__(16) char smem[65536];   // 4 waves x (2 slots x 8 KB)

    const int tid  = threadIdx.x;
    const int lane = tid & 63;
    const int cg   = tid >> 6;     // kv-slice wave: handles kvblk = it*4 + cg
    const int h    = lane >> 5;
    const int l31  = lane & 31;

    const int b  = blockIdx.x & 7;
    const int q0 = (blockIdx.x >> 3) * 32;

    const char* kfb = (const char*)(kf + (size_t)b * 131072);
    const char* vfb = (const char*)(vf + (size_t)b * 131072);
    char* ring = smem + cg * 16384;

    // Q B-frags, pre-scaled by 0.125*log2e then fp32->bf16
    constexpr float QSCALE = 0.125f * 1.4426950408889634f;
    bf16x8 qf[4];
    {
        const float* qp = q + ((size_t)b * N + q0 + l31) * D + h * 8;
        #pragma unroll
        for (int kd = 0; kd < 4; ++kd) {
            floatx4 f0 = *(const floatx4*)(qp + kd * 16);
            floatx4 f1 = *(const floatx4*)(qp + kd * 16 + 4);
            bf16x8 t;
            #pragma unroll
            for (int j = 0; j < 4; ++j) {
                t[j]     = (bf16_t)(f0[j] * QSCALE);
                t[j + 4] = (bf16_t)(f1[j] * QSCALE);
            }
            qf[kd] = t;
        }
    }

    // prologue: stage kvblk=cg into slot 0 (8 async loads)
    {
        const char* kc = kfb + (size_t)cg * 4096;
        const char* vc = vfb + (size_t)cg * 4096;
        #pragma unroll
        for (int j = 0; j < 4; ++j) {
            gload_lds16(kc + j * 1024 + lane * 16, ring + j * 1024);
            gload_lds16(vc + j * 1024 + lane * 16, ring + 4096 + j * 1024);
        }
    }

    floatx16 o_acc[2];
    #pragma unroll
    for (int d = 0; d < 2; ++d)
        #pragma unroll
        for (int i = 0; i < 16; ++i) o_acc[d][i] = 0.f;
    float l_run0 = 0.f, l_run1 = 0.f;

    #pragma unroll
    for (int it = 0; it < 16; ++it) {
        char* cur = ring + (it & 1) * 8192;

        if (it < 15) {
            // stage kvblk for it+1 into the other slot; stays in flight across
            // this whole iteration (issue->wait distance = one full iteration)
            char* nxt = ring + ((it + 1) & 1) * 8192;
            const char* kc = kfb + (size_t)((it + 1) * 4 + cg) * 4096;
            const char* vc = vfb + (size_t)((it + 1) * 4 + cg) * 4096;
            #pragma unroll
            for (int j = 0; j < 4; ++j) {
                gload_lds16(kc + j * 1024 + lane * 16, nxt + j * 1024);
                gload_lds16(vc + j * 1024 + lane * 16, nxt + 4096 + j * 1024);
            }
            asm volatile("s_waitcnt vmcnt(8)" ::: "memory");  // cur's 8 done, nxt's 8 in flight
        } else {
            asm volatile("s_waitcnt vmcnt(0)" ::: "memory");  // drain (also fences epilogue reuse)
        }

        // LDS -> regs (conflict-free ds_read_b128 at lane*16)
        bf16x8 kreg[4], vreg[4];
        #pragma unroll
        for (int kd = 0; kd < 4; ++kd) {
            kreg[kd] = *(const bf16x8*)(cur + kd * 1024 + lane * 16);
            vreg[kd] = *(const bf16x8*)(cur + 4096 + kd * 1024 + lane * 16);
        }

        // S^T(log2-domain) = K (Q*0.125*log2e)^T (32kv x 32q)
        floatx16 s;
        #pragma unroll
        for (int i = 0; i < 16; ++i) s[i] = 0.f;
        __builtin_amdgcn_s_setprio(1);
        #pragma unroll
        for (int kd = 0; kd < 4; ++kd)
            s = __builtin_amdgcn_mfma_f32_32x32x16_bf16(kreg[kd], qf[kd], s, 0, 0, 0);
        __builtin_amdgcn_s_setprio(0);

        // equality-mask (attn==0 -> -inf -> weight 0) + exp2; pack bf16 pairs
        int q8[8];
        #pragma unroll
        for (int g = 0; g < 8; ++g) {
            union { int i; bf16x2 h2; } u;
            {
                float x = s[2 * g + 0];
                float p = (x == 0.0f) ? 0.0f : __builtin_amdgcn_exp2f(x);
                l_run0 += p;
                u.h2[0] = (bf16_t)p;
            }
            {
                float x = s[2 * g + 1];
                float p = (x == 0.0f) ? 0.0f : __builtin_amdgcn_exp2f(x);
                l_run1 += p;
                u.h2[1] = (bf16_t)p;
            }
            q8[g] = u.i;
        }

        // O^T += V^T P^T : A = V-frag, B = P^T-frag via permlane32_swap (both
        // returned words are exactly the two B-frag halves)
        #pragma unroll
        for (int s2 = 0; s2 < 2; ++s2) {
            intx2 p02 = __builtin_amdgcn_permlane32_swap(q8[4 * s2 + 0], q8[4 * s2 + 2], false, false);
            intx2 p13 = __builtin_amdgcn_permlane32_swap(q8[4 * s2 + 1], q8[4 * s2 + 3], false, false);
            union { int i4[4]; bf16x8 v; } bf;
            bf.i4[0] = p02[0];
            bf.i4[1] = p13[0];
            bf.i4[2] = p02[1];
            bf.i4[3] = p13[1];
            __builtin_amdgcn_s_setprio(1);
            #pragma unroll
            for (int dblk = 0; dblk < 2; ++dblk)
                o_acc[dblk] = __builtin_amdgcn_mfma_f32_32x32x16_bf16(vreg[s2 * 2 + dblk], bf.v,
                                                                      o_acc[dblk], 0, 0, 0);
            __builtin_amdgcn_s_setprio(0);
        }
    }

    // complete this lane's denom (partner half-wave holds the other 16 kv rows)
    float l_run = l_run0 + l_run1;
    l_run += __shfl_xor(l_run, 32);

    // epilogue: ring LDS (dead now, vmcnt(0) drained) reused as merge buffer.
    // wave cg's partials at its own ring base; then merge split 4 ways.
    {
        float* ob = (float*)ring;                 // 2048 floats = 8 KB
        #pragma unroll
        for (int dblk = 0; dblk < 2; ++dblk)
            #pragma unroll
            for (int i = 0; i < 16; ++i) {
                const int d = (i & 3) + 8 * (i >> 2) + 4 * h + dblk * 32;
                ob[d * 32 + l31] = o_acc[dblk][i];
            }
        if (h == 0) ((float*)(ring + 8192))[l31] = l_run;
    }
    __syncthreads();
    {
        const int mdblk = cg & 1;                 // wave's merge quadrant
        const int g0 = (cg >> 1) * 2;
        float lsum = 0.f;
        #pragma unroll
        for (int w = 0; w < 4; ++w) lsum += ((const float*)(smem + w * 16384 + 8192))[l31];
        const float inv_l = 1.0f / lsum;
        float* op = out + ((size_t)b * N + q0 + l31) * D;
        #pragma unroll
        for (int gg = 0; gg < 2; ++gg) {
            const int d0 = 8 * (g0 + gg) + 4 * h + mdblk * 32;
            floatx4 o4;
            #pragma unroll
            for (int j = 0; j < 4; ++j) {
                float sum = 0.f;
                #pragma unroll
                for (int w = 0; w < 4; ++w)
                    sum += ((const float*)(smem + w * 16384))[(d0 + j) * 32 + l31];
                o4[j] = sum * inv_l;
            }
            *(floatx4*)(op + d0) = o4;
        }
    }
}

extern "C" void kernel_launch(void* const* d_in, const int* in_sizes, int n_in,
                              void* d_out, int out_size, void* d_ws, size_t ws_size,
                              hipStream_t stream) {
    const float* q = (const float*)d_in[0];
    const float* k = (const float*)d_in[1];
    const float* v = (const float*)d_in[2];
    float* out = (float*)d_out;
    bf16_t* kfrag = (bf16_t*)d_ws;                                    // 2 MB
    bf16_t* vfrag = (bf16_t*)((char*)d_ws + (size_t)B * N * D * 2);   // 2 MB

    hipLaunchKernelGGL(prepass_kernel, dim3(512), dim3(256), 0, stream, k, v, kfrag, vfrag);
    hipLaunchKernelGGL(attn_kernel, dim3(512), dim3(256), 0, stream, q, kfrag, vfrag, out);
}